// Round 8
// baseline (156.434 us; speedup 1.0000x reference)
//
#include <hip/hip_runtime.h>

// TorchNeighborList, N=4096, cutoff=5, no PBC.
// Output layout (float32, flat; P = N(N-1)/2 = 8,386,560; TP = 2P rows):
//   [0,TP) idx_i | [TP,2TP) idx_j | [2TP,5TP) Rij | [5TP,8TP) cell_offset
//   [8TP,9TP) mask | [9TP] num_pairs
// Ordering: stable argsort by source idx of concat(triu_i, triu_j) ->
//   per atom a: partners j>a ascending, then i<a ascending.
// Valid rows are the dense prefix [0, np). Padding: idx=4096, Rij=0, mask=0.
//
// R7 budget: fills 604 MB ~135 us (4.6 TB/s sustained rocclr memset — custom
// fill kernels plateau lower; per-dispatch rocprof durs for fills are bogus),
// count ~3, scatter ~8, node overhead ~4. This round: count stores validity
// ballots (2 MB) so scatter skips the distance recompute (mask-driven writes).

#define NA 4096
static constexpr int PP = 8386560;             // N(N-1)/2
static constexpr int TP = 2 * PP;              // 16,773,120 rows
static constexpr int NF = 9 * TP;              // 150,958,080 floats (excl. num_pairs)

__device__ __forceinline__ float dist2_exact(float dx, float dy, float dz) {
    return __fadd_rn(__fadd_rn(__fmul_rn(dx, dx), __fmul_rn(dy, dy)),
                     __fmul_rn(dz, dz));
}

// ---- K1a: per-atom count + validity ballots (1 wave per atom) ------------
// masks[a*64 + c] = ballot over partners p = c*64+lane of (p!=a && dist<5).
__global__ void count_mask_kernel(const float* __restrict__ pos, int* __restrict__ cnt,
                                  unsigned long long* __restrict__ masks) {
    int wid = threadIdx.x >> 6, lane = threadIdx.x & 63;
    int a = blockIdx.x * 4 + wid;
    float ax = pos[3 * a + 0], ay = pos[3 * a + 1], az = pos[3 * a + 2];
    int c = 0;
    unsigned long long mym = 0;          // lane l keeps chunk l's mask
    for (int chk = 0; chk < 64; ++chk) {
        int p = chk * 64 + lane;
        float dx = pos[3 * p + 0] - ax;
        float dy = pos[3 * p + 1] - ay;
        float dz = pos[3 * p + 2] - az;
        bool valid = (p != a) && (__fsqrt_rn(dist2_exact(dx, dy, dz)) < 5.0f);
        unsigned long long m = __ballot(valid);
        if (lane == chk) mym = m;
        c += __popcll(m);                // same value in every lane
    }
    masks[(long long)a * 64 + lane] = mym;   // one coalesced 8B store per lane
    if (lane == 0) cnt[a] = c;
}

// ---- K2a: prefix + mask-driven scatter (1 wave per atom, no recompute) ---
__global__ void scatter_mask_kernel(const float* __restrict__ pos, const int* __restrict__ cnt,
                                    const unsigned long long* __restrict__ masks,
                                    float* __restrict__ out) {
    int wid = threadIdx.x >> 6, lane = threadIdx.x & 63;
    int a = blockIdx.x * 4 + wid;
    float ax = pos[3 * a + 0], ay = pos[3 * a + 1], az = pos[3 * a + 2];

    // exclusive prefix over cnt[0..a)  (16 KB, L2-resident)
    int s = 0;
    for (int i = lane; i < a; i += 64) s += cnt[i];
    for (int off = 32; off; off >>= 1) s += __shfl_down(s, off, 64);
    int o = __shfl(s, 0, 64);
    if (a == NA - 1 && lane == 0) out[NF] = (float)(o + cnt[a]);   // num_pairs

    const unsigned long long* ma = masks + (long long)a * 64;
    int ca = a >> 6, abit = a & 63;
    unsigned long long lanebelow = (1ull << lane) - 1ull;

    // phase 0: partners p > a (chunks ca..63; first chunk keeps bits > abit)
    for (int chk = ca; chk < 64; ++chk) {
        unsigned long long m = ma[chk];
        if (chk == ca) m &= ~((2ull << abit) - 1ull);   // abit=63 -> 0 mask, ok
        if (!m) { continue; }
        if ((m >> lane) & 1ull) {
            int p = chk * 64 + lane;
            float px = pos[3 * p + 0], py = pos[3 * p + 1], pz = pos[3 * p + 2];
            int idx = o + __popcll(m & lanebelow);
            out[idx] = (float)a;                      // idx_i
            out[TP + idx] = (float)p;                 // idx_j
            int r = 2 * TP + 3 * idx;                 // Rij row
            out[r + 0] = px - ax;
            out[r + 1] = py - ay;
            out[r + 2] = pz - az;
            out[8 * TP + idx] = 1.0f;                 // mask
        }
        o += __popcll(m);
    }
    // phase 1: partners p < a (chunks 0..ca; last chunk keeps bits < abit)
    for (int chk = 0; chk <= ca; ++chk) {
        unsigned long long m = ma[chk];
        if (chk == ca) m &= (1ull << abit) - 1ull;      // abit=0 -> 0 mask, ok
        if (!m) { continue; }
        if ((m >> lane) & 1ull) {
            int p = chk * 64 + lane;
            float px = pos[3 * p + 0], py = pos[3 * p + 1], pz = pos[3 * p + 2];
            int idx = o + __popcll(m & lanebelow);
            out[idx] = (float)a;
            out[TP + idx] = (float)p;
            int r = 2 * TP + 3 * idx;
            out[r + 0] = px - ax;
            out[r + 1] = py - ay;
            out[r + 2] = pz - az;
            out[8 * TP + idx] = 1.0f;
        }
        o += __popcll(m);
    }
}

// ---- Fallback pair (R7 path, used if ws_size < masks requirement) --------
__global__ void count_kernel(const float* __restrict__ pos, int* __restrict__ cnt) {
    int wid = threadIdx.x >> 6, lane = threadIdx.x & 63;
    int a = blockIdx.x * 4 + wid;
    float ax = pos[3 * a + 0], ay = pos[3 * a + 1], az = pos[3 * a + 2];
    int c = 0;
    for (int base = 0; base < NA; base += 64) {
        int p = base + lane;
        float dx = pos[3 * p + 0] - ax;
        float dy = pos[3 * p + 1] - ay;
        float dz = pos[3 * p + 2] - az;
        if (p != a && __fsqrt_rn(dist2_exact(dx, dy, dz)) < 5.0f) c++;
    }
    for (int off = 32; off; off >>= 1) c += __shfl_down(c, off, 64);
    if (lane == 0) cnt[a] = c;
}

__global__ void scatter_kernel(const float* __restrict__ pos, const int* __restrict__ cnt,
                               float* __restrict__ out) {
    int wid = threadIdx.x >> 6, lane = threadIdx.x & 63;
    int a = blockIdx.x * 4 + wid;
    float ax = pos[3 * a + 0], ay = pos[3 * a + 1], az = pos[3 * a + 2];
    int s = 0;
    for (int i = lane; i < a; i += 64) s += cnt[i];
    for (int off = 32; off; off >>= 1) s += __shfl_down(s, off, 64);
    int o = __shfl(s, 0, 64);
    if (a == NA - 1 && lane == 0) out[NF] = (float)(o + cnt[a]);
    for (int phase = 0; phase < 2; ++phase) {
        int lo = (phase == 0) ? a + 1 : 0;
        int hi = (phase == 0) ? NA : a;
        for (int base = lo & ~63; base < hi; base += 64) {
            int p = base + lane;
            bool valid = (p >= lo) && (p < hi);
            float px = 0.f, py = 0.f, pz = 0.f;
            if (valid) {
                px = pos[3 * p + 0]; py = pos[3 * p + 1]; pz = pos[3 * p + 2];
                valid = __fsqrt_rn(dist2_exact(px - ax, py - ay, pz - az)) < 5.0f;
            }
            unsigned long long m = __ballot(valid);
            if (valid) {
                int idx = o + __popcll(m & ((1ull << lane) - 1ull));
                out[idx] = (float)a;
                out[TP + idx] = (float)p;
                int r = 2 * TP + 3 * idx;
                out[r + 0] = px - ax;
                out[r + 1] = py - ay;
                out[r + 2] = pz - az;
                out[8 * TP + idx] = 1.0f;
            }
            o += __popcll(m);
        }
    }
}

extern "C" void kernel_launch(void* const* d_in, const int* in_sizes, int n_in,
                              void* d_out, int out_size, void* d_ws, size_t ws_size,
                              hipStream_t stream) {
    const float* pos = (const float*)d_in[0];   // [4096,3] f32
    float* out = (float*)d_out;
    int* cnt = (int*)d_ws;                                   // 16 KB
    unsigned long long* masks = (unsigned long long*)((char*)d_ws + 32768);
    size_t need = 32768 + (size_t)NA * 64 * 8;               // 32 KB + 2 MB

    if (ws_size >= need) {
        count_mask_kernel<<<NA / 4, 256, 0, stream>>>(pos, cnt, masks);
    } else {
        count_kernel<<<NA / 4, 256, 0, stream>>>(pos, cnt);
    }
    // idx_i + idx_j regions <- 4096.0f (bits 0x45800000), 2*TP words = 134 MB
    hipMemsetD32Async((hipDeviceptr_t)out, 0x45800000, (size_t)2 * TP, stream);
    // Rij + cell_offset + mask regions <- 0, 7*TP floats = 470 MB
    hipMemsetAsync(out + (size_t)2 * TP, 0, (size_t)7 * TP * sizeof(float), stream);
    if (ws_size >= need) {
        scatter_mask_kernel<<<NA / 4, 256, 0, stream>>>(pos, cnt, masks, out);
    } else {
        scatter_kernel<<<NA / 4, 256, 0, stream>>>(pos, cnt, out);
    }
}

// Round 9
// 149.816 us; speedup vs baseline: 1.0442x; 1.0442x over previous
//
#include <hip/hip_runtime.h>

// TorchNeighborList, N=4096, cutoff=5, no PBC.
// Output layout (float32, flat; P = N(N-1)/2 = 8,386,560; TP = 2P rows):
//   [0,TP) idx_i | [TP,2TP) idx_j | [2TP,5TP) Rij | [5TP,8TP) cell_offset
//   [8TP,9TP) mask | [9TP] num_pairs
// Ordering: stable argsort by source idx of concat(triu_i, triu_j) ->
//   per atom a: partners j>a ascending, then i<a ascending.
// Valid rows are the dense prefix [0, np). Padding: idx=4096, Rij=0, mask=0.
//
// Final structure (R7, best known = 150.2 us):
//   count (3us) -> memsetD32 sentinel 134 MB -> memset0 470 MB (together
//   ~131 us @ ~4.6 TB/s sustained rocclr fill rate) -> scatter (~8 us,
//   inline prefix-scan + rank-ordered compaction).
// R8's mask-cache variant regressed (+6 us) — distance recompute in scatter
// was never the cost; reverted.

#define NA 4096
static constexpr int PP = 8386560;             // N(N-1)/2
static constexpr int TP = 2 * PP;              // 16,773,120 rows
static constexpr int NF = 9 * TP;              // 150,958,080 floats (excl. num_pairs)

__device__ __forceinline__ float dist2_exact(float dx, float dy, float dz) {
    return __fadd_rn(__fadd_rn(__fmul_rn(dx, dx), __fmul_rn(dy, dy)),
                     __fmul_rn(dz, dz));
}

// ---- K1: per-atom neighbor count (1 wave per atom) -----------------------
__global__ void count_kernel(const float* __restrict__ pos, int* __restrict__ cnt) {
    int wid = threadIdx.x >> 6, lane = threadIdx.x & 63;
    int a = blockIdx.x * 4 + wid;
    float ax = pos[3 * a + 0], ay = pos[3 * a + 1], az = pos[3 * a + 2];
    int c = 0;
    for (int base = 0; base < NA; base += 64) {
        int p = base + lane;
        float dx = pos[3 * p + 0] - ax;
        float dy = pos[3 * p + 1] - ay;
        float dz = pos[3 * p + 2] - az;
        if (p != a && __fsqrt_rn(dist2_exact(dx, dy, dz)) < 5.0f) c++;
    }
    for (int off = 32; off; off >>= 1) c += __shfl_down(c, off, 64);
    if (lane == 0) cnt[a] = c;
}

// ---- K2: inline exclusive scan + rank-ordered scatter (1 wave per atom) --
__global__ void scatter_kernel(const float* __restrict__ pos, const int* __restrict__ cnt,
                               float* __restrict__ out) {
    int wid = threadIdx.x >> 6, lane = threadIdx.x & 63;
    int a = blockIdx.x * 4 + wid;
    float ax = pos[3 * a + 0], ay = pos[3 * a + 1], az = pos[3 * a + 2];

    // exclusive prefix over cnt[0..a)  (cnt = 16 KB, L2-resident)
    int s = 0;
    for (int i = lane; i < a; i += 64) s += cnt[i];
    for (int off = 32; off; off >>= 1) s += __shfl_down(s, off, 64);
    int o = __shfl(s, 0, 64);

    if (a == NA - 1 && lane == 0) out[NF] = (float)(o + cnt[a]);   // num_pairs

    // phase 0: partners > a ascending; phase 1: partners < a ascending
    for (int phase = 0; phase < 2; ++phase) {
        int lo = (phase == 0) ? a + 1 : 0;
        int hi = (phase == 0) ? NA : a;
        for (int base = lo & ~63; base < hi; base += 64) {
            int p = base + lane;
            bool valid = (p >= lo) && (p < hi);
            float px = 0.f, py = 0.f, pz = 0.f;
            if (valid) {
                px = pos[3 * p + 0]; py = pos[3 * p + 1]; pz = pos[3 * p + 2];
                valid = __fsqrt_rn(dist2_exact(px - ax, py - ay, pz - az)) < 5.0f;
            }
            unsigned long long m = __ballot(valid);
            if (valid) {
                int idx = o + __popcll(m & ((1ull << lane) - 1ull));
                out[idx] = (float)a;                      // idx_i
                out[TP + idx] = (float)p;                 // idx_j
                int r = 2 * TP + 3 * idx;                 // Rij row
                out[r + 0] = px - ax;
                out[r + 1] = py - ay;
                out[r + 2] = pz - az;
                out[8 * TP + idx] = 1.0f;                 // mask
            }
            o += __popcll(m);
        }
    }
}

extern "C" void kernel_launch(void* const* d_in, const int* in_sizes, int n_in,
                              void* d_out, int out_size, void* d_ws, size_t ws_size,
                              hipStream_t stream) {
    const float* pos = (const float*)d_in[0];   // [4096,3] f32
    float* out = (float*)d_out;
    int* cnt = (int*)d_ws;          // [0,4096)

    count_kernel<<<NA / 4, 256, 0, stream>>>(pos, cnt);
    // idx_i + idx_j regions <- 4096.0f (bits 0x45800000), 2*TP words = 134 MB
    hipMemsetD32Async((hipDeviceptr_t)out, 0x45800000, (size_t)2 * TP, stream);
    // Rij + cell_offset + mask regions <- 0, 7*TP floats = 470 MB
    hipMemsetAsync(out + (size_t)2 * TP, 0, (size_t)7 * TP * sizeof(float), stream);
    scatter_kernel<<<NA / 4, 256, 0, stream>>>(pos, cnt, out);
}